// Round 1
// baseline (169268.823 us; speedup 1.0000x reference)
//
#include <hip/hip_runtime.h>
#include <cstdint>
#include <cstddef>

#define TPB 256
#define NB  256

typedef float4 f4;

// ---------------- JAX Threefry-2x32 (partitionable variant) ----------------
__device__ __forceinline__ void tf2x32(uint32_t k0, uint32_t k1, uint32_t x0, uint32_t x1,
                                       uint32_t& o0, uint32_t& o1) {
  uint32_t ks2 = k0 ^ k1 ^ 0x1BD11BDAu;
  x0 += k0; x1 += k1;
#define TFR(r) { x0 += x1; x1 = (x1 << (r)) | (x1 >> (32 - (r))); x1 ^= x0; }
  TFR(13) TFR(15) TFR(26) TFR(6)
  x0 += k1;  x1 += ks2 + 1u;
  TFR(17) TFR(29) TFR(16) TFR(24)
  x0 += ks2; x1 += k0 + 2u;
  TFR(13) TFR(15) TFR(26) TFR(6)
  x0 += k0;  x1 += k1 + 3u;
  TFR(17) TFR(29) TFR(16) TFR(24)
  x0 += k1;  x1 += ks2 + 4u;
  TFR(13) TFR(15) TFR(26) TFR(6)
  x0 += ks2; x1 += k0 + 5u;
#undef TFR
  o0 = x0; o1 = x1;
}

__device__ __forceinline__ uint32_t tf_fold(uint32_t k0, uint32_t k1, uint32_t idx) {
  uint32_t a, b; tf2x32(k0, k1, 0u, idx, a, b); return a ^ b;  // 32-bit partitionable bits
}

// ---------------- helpers ----------------
__device__ __forceinline__ float dot_f4(const float* __restrict__ x, const float* __restrict__ w, int n4) {
  const f4* xv = (const f4*)x; const f4* wv = (const f4*)w;
  float sx = 0.f, sy = 0.f, sz = 0.f, sw = 0.f;
#pragma unroll 8
  for (int k = 0; k < n4; ++k) {
    f4 a = xv[k], b = wv[k];
    sx = fmaf(a.x, b.x, sx); sy = fmaf(a.y, b.y, sy);
    sz = fmaf(a.z, b.z, sz); sw = fmaf(a.w, b.w, sw);
  }
  return (sx + sy) + (sz + sw);
}

__device__ __forceinline__ float sigm(float x) { return 1.f / (1.f + expf(-x)); }

__device__ __forceinline__ void grid_sync(unsigned* bar) {
  __syncthreads();
  if (threadIdx.x == 0) {
    __threadfence();
    unsigned g = __hip_atomic_load(bar + 1, __ATOMIC_RELAXED, __HIP_MEMORY_SCOPE_AGENT);
    unsigned a = __hip_atomic_fetch_add(bar, 1u, __ATOMIC_ACQ_REL, __HIP_MEMORY_SCOPE_AGENT);
    if (a == (unsigned)(NB - 1)) {
      __hip_atomic_store(bar, 0u, __ATOMIC_RELAXED, __HIP_MEMORY_SCOPE_AGENT);
      __hip_atomic_store(bar + 1, g + 1u, __ATOMIC_RELEASE, __HIP_MEMORY_SCOPE_AGENT);
    } else {
      while (__hip_atomic_load(bar + 1, __ATOMIC_ACQUIRE, __HIP_MEMORY_SCOPE_AGENT) == g)
        __builtin_amdgcn_s_sleep(1);
    }
  }
  __syncthreads();
}

// ws layout (floats): [0..16) barrier | ah[2][16][1024] | ac[16][1024] | dh[2][16][1024] |
//                     dc[16][1024] | actx[2][16][512] | dec_ins[200][16][256] | pmem[16][256][128]
#define WS_AH   16
#define WS_AC   (WS_AH + 32768)
#define WS_DH   (WS_AC + 16384)
#define WS_DC   (WS_DH + 32768)
#define WS_ACTX (WS_DC + 16384)
#define WS_DEC  (WS_ACTX + 16384)
#define WS_PMEM (WS_DEC + 819200)
#define WS_STATE_BYTES (WS_DEC * 4)   // zero: barrier + all recurrent state

__global__ __launch_bounds__(TPB) void decoder_persistent_kernel(
    const float* __restrict__ memory, const float* __restrict__ dec_inp,
    const int* __restrict__ mem_len,
    const float* __restrict__ pw1, const float* __restrict__ pw2,
    const float* __restrict__ a_wih, const float* __restrict__ a_whh, const float* __restrict__ a_b,
    const float* __restrict__ d_wih, const float* __restrict__ d_whh, const float* __restrict__ d_b,
    const float* __restrict__ proj_w, const float* __restrict__ proj_b,
    const float* __restrict__ query_w, const float* __restrict__ memory_w,
    const float* __restrict__ v_w, const float* __restrict__ conv_w, const float* __restrict__ ldw,
    float* __restrict__ out, float* __restrict__ ws) {
  __shared__ float smem[7168];   // 28 KiB, carved per phase

  unsigned* bar = (unsigned*)ws;
  float* ah      = ws + WS_AH;
  float* ac      = ws + WS_AC;
  float* dh      = ws + WS_DH;
  float* dc      = ws + WS_DC;
  float* actx    = ws + WS_ACTX;
  float* dec_ins = ws + WS_DEC;
  float* pmem    = ws + WS_PMEM;

  const int tid = threadIdx.x;

  // ---------------- P0a: prenet -> dec_ins [200][16][256] ----------------
  {
    uint32_t d00, d01, d10, d11;
    tf2x32(0u, 42u, 0u, 0u, d00, d01);   // split(key(42),2)[0]  (fold-like split)
    tf2x32(0u, 42u, 0u, 1u, d10, d11);   // split(key(42),2)[1]
    float* xin = smem;         // 80
    float* h1  = smem + 128;   // 256
    for (int task = blockIdx.x; task < 3200; task += NB) {
      int tt = task >> 4, b = task & 15;
      if (tid < 80)
        xin[tid] = (tt == 0) ? 0.f : dec_inp[(size_t)b * 16000 + tid * 200 + (tt - 1)];
      __syncthreads();
      // layer 1: relu(x @ w1.T) then dropout(keep*2)
      float acc = 0.f;
      const float* w1r = pw1 + tid * 80;
#pragma unroll 4
      for (int mm = 0; mm < 80; ++mm) acc = fmaf(xin[mm], w1r[mm], acc);
      acc = fmaxf(acc, 0.f);
      uint32_t idx = ((uint32_t)tt * 16u + (uint32_t)b) * 256u + (uint32_t)tid;
      acc = (tf_fold(d00, d01, idx) >> 31) ? 0.f : acc * 2.f;  // keep iff bits < 2^31
      h1[tid] = acc;
      __syncthreads();
      // layer 2
      float acc2 = 0.f;
      const float* w2r = pw2 + tid * 256;
#pragma unroll 4
      for (int pp = 0; pp < 256; ++pp) acc2 = fmaf(h1[pp], w2r[pp], acc2);
      acc2 = fmaxf(acc2, 0.f);
      acc2 = (tf_fold(d10, d11, idx) >> 31) ? 0.f : acc2 * 2.f;
      dec_ins[(size_t)task * 256 + tid] = acc2;
      __syncthreads();
    }
  }
  // ---------------- P0b: pmem = memory @ memory_w.T  [16][256][128] ----------------
  for (int task = blockIdx.x; task < 4096; task += NB) {
    if (tid < 128) {
      float acc = dot_f4(memory + (size_t)task * 512, memory_w + (size_t)tid * 512, 128);
      pmem[(size_t)task * 128 + tid] = acc;
    }
  }
  grid_sync(bar);

  // ---------------- 200 sequential steps ----------------
  for (int t = 0; t < 200; ++t) {
    const int cur = t & 1, prv = cur ^ 1;

    // ---- Stage A: attention LSTM (fused gates + pointwise) ----
    {
      int gid  = blockIdx.x * TPB + tid;
      int j    = gid >> 6;           // 0..1023
      int lane = tid & 63;
      int g    = lane >> 4, b = lane & 15;
      int row  = g * 1024 + j;       // gate order i,f,g,o
      const float* wih = a_wih + (size_t)row * 768;
      float acc = a_b[row];
      acc += dot_f4(dec_ins + ((size_t)t * 16 + b) * 256, wih, 64);
      acc += dot_f4(actx + prv * 8192 + b * 512, wih + 256, 128);
      acc += dot_f4(ah + prv * 16384 + b * 1024, a_whh + (size_t)row * 1024, 256);
      float fv = __shfl(acc, b + 16, 64);
      float gg = __shfl(acc, b + 32, 64);
      float ov = __shfl(acc, b + 48, 64);
      if (lane < 16) {
        int ci = b * 1024 + j;
        float c2 = sigm(fv) * ac[ci] + sigm(acc) * tanhf(gg);
        ac[ci] = c2;
        ah[cur * 16384 + ci] = sigm(ov) * tanhf(c2);
      }
    }
    grid_sync(bar);

    // ---- Stage B: attention (blocks 0..15) || projection of step t-1 (blocks 16..31) ----
    if (blockIdx.x < 16) {
      int b = blockIdx.x;
      float* aw_s  = smem;          // 256  (persistent across steps; only tail [128,256) nonzero)
      float* awc_s = smem + 256;    // 256  (persistent)
      float* convw = smem + 512;    // 62*32, [ (c*31+k)*32 + o ]
      float* ldw_s = smem + 2496;   // 128*32
      float* vw_s  = smem + 6592;   // 128
      float* q_s   = smem + 6720;   // 128
      float* epair = smem + 6848;   // 256
      float* red_s = smem + 7104;   // 16
      if (t == 0) {
        for (int i = tid; i < 1984; i += TPB) { int o = i & 31, ck = i >> 5; convw[i] = conv_w[o * 62 + ck]; }
        for (int i = tid; i < 4096; i += TPB) ldw_s[i] = ldw[i];
        if (tid < 128) vw_s[tid] = v_w[tid];
        aw_s[tid] = 0.f; awc_s[tid] = 0.f;
      }
      __syncthreads();
      // query = ah_new @ query_w.T
      if (tid < 128) q_s[tid] = dot_f4(ah + cur * 16384 + b * 1024, query_w + (size_t)tid * 1024, 256);
      __syncthreads();
      // conv + dense + energies; only tt in [128,256) can be unmasked (len >= 128)
      {
        int half = tid >> 7, ttl = tid & 127, tt = 128 + ttl;
        float loc[32];
#pragma unroll
        for (int o = 0; o < 32; ++o) loc[o] = 0.f;
        for (int c = 0; c < 2; ++c) {
          const float* src = c ? awc_s : aw_s;
          for (int k = 0; k < 31; ++k) {
            int p = tt - 15 + k;                    // >= 113 always
            float v = (p < 256) ? src[p] : 0.f;
            const float* wr = convw + (c * 31 + k) * 32;
#pragma unroll
            for (int o = 0; o < 32; ++o) loc[o] = fmaf(v, wr[o], loc[o]);
          }
        }
        float e = 0.f;
        const float* pm = pmem + ((size_t)(b * 256 + tt)) * 128 + half * 64;
        const float* qh = q_s + half * 64;
        const float* vh = vw_s + half * 64;
        for (int a = 0; a < 64; ++a) {
          const float* lr = ldw_s + (half * 64 + a) * 32;
          float locd = 0.f;
#pragma unroll
          for (int o = 0; o < 32; ++o) locd = fmaf(loc[o], lr[o], locd);
          float s = qh[a] + locd + pm[a];
          s = fminf(20.f, fmaxf(-20.f, s));
          e = fmaf(tanhf(s), vh[a], e);
        }
        epair[tid] = e;
      }
      __syncthreads();
      // masked softmax over tt (mask: tt < len  ->  -inf)
      int lenb = mem_len[b];
      float e = 0.f; bool live = false;
      if (tid < 128) { e = epair[tid] + epair[tid + 128]; live = (128 + tid) >= lenb; }
      float sc = live ? e : -3.4e38f;
#pragma unroll
      for (int off = 32; off; off >>= 1) sc = fmaxf(sc, __shfl_xor(sc, off, 64));
      if ((tid & 63) == 0) red_s[tid >> 6] = sc;
      __syncthreads();
      float mx = fmaxf(fmaxf(red_s[0], red_s[1]), fmaxf(red_s[2], red_s[3]));
      float p = live ? expf(e - mx) : 0.f;
      float z = p;
#pragma unroll
      for (int off = 32; off; off >>= 1) z += __shfl_xor(z, off, 64);
      if ((tid & 63) == 0) red_s[4 + (tid >> 6)] = z;
      __syncthreads();
      z = red_s[4] + red_s[5] + red_s[6] + red_s[7];
      if (tid < 128) {
        float awv = p / z;
        aw_s[128 + tid] = awv;
        awc_s[128 + tid] += awv;
      }
      __syncthreads();
      // actx = aw @ memory  (rows < len have aw == 0 exactly)
      for (int e0 = tid; e0 < 512; e0 += TPB) {
        float acc2 = 0.f;
        for (int tt2 = lenb; tt2 < 256; ++tt2)
          acc2 = fmaf(aw_s[tt2], memory[((size_t)(b * 256 + tt2)) * 512 + e0], acc2);
        actx[cur * 8192 + b * 512 + e0] = acc2;
      }
    } else if (blockIdx.x < 32 && t > 0) {
      // projection for step t-1 (overlapped)
      int b = blockIdx.x - 16, m = tid;
      if (m < 80) {
        const float* pw = proj_w + (size_t)m * 1536;
        float acc = proj_b[m];
        acc += dot_f4(dh + prv * 16384 + b * 1024, pw, 256);
        acc += dot_f4(actx + prv * 8192 + b * 512, pw + 1024, 128);
        out[(size_t)b * 16000 + m * 200 + (t - 1)] = acc;
      }
    }
    grid_sync(bar);

    // ---- Stage C: decoder LSTM ----
    {
      int gid  = blockIdx.x * TPB + tid;
      int j    = gid >> 6;
      int lane = tid & 63;
      int g    = lane >> 4, b = lane & 15;
      int row  = g * 1024 + j;
      const float* wih = d_wih + (size_t)row * 1536;
      float acc = d_b[row];
      acc += dot_f4(ah + cur * 16384 + b * 1024, wih, 256);
      acc += dot_f4(actx + cur * 8192 + b * 512, wih + 1024, 128);
      acc += dot_f4(dh + prv * 16384 + b * 1024, d_whh + (size_t)row * 1024, 256);
      float fv = __shfl(acc, b + 16, 64);
      float gg = __shfl(acc, b + 32, 64);
      float ov = __shfl(acc, b + 48, 64);
      if (lane < 16) {
        int ci = b * 1024 + j;
        float c2 = sigm(fv) * dc[ci] + sigm(acc) * tanhf(gg);
        dc[ci] = c2;
        dh[cur * 16384 + ci] = sigm(ov) * tanhf(c2);
      }
    }
    grid_sync(bar);
  }

  // ---- final projection for t = 199 (buffers at parity 1) ----
  if (blockIdx.x >= 16 && blockIdx.x < 32) {
    int b = blockIdx.x - 16, m = tid;
    if (m < 80) {
      const float* pw = proj_w + (size_t)m * 1536;
      float acc = proj_b[m];
      acc += dot_f4(dh + 16384 + b * 1024, pw, 256);
      acc += dot_f4(actx + 8192 + b * 512, pw + 1024, 128);
      out[(size_t)b * 16000 + m * 200 + 199] = acc;
    }
  }
}

extern "C" void kernel_launch(void* const* d_in, const int* in_sizes, int n_in,
                              void* d_out, int out_size, void* d_ws, size_t ws_size,
                              hipStream_t stream) {
  (void)in_sizes; (void)n_in; (void)out_size; (void)ws_size;
  const float* memory   = (const float*)d_in[0];
  const float* dec_inp  = (const float*)d_in[1];
  const int*   mem_len  = (const int*)d_in[2];
  const float* pw1      = (const float*)d_in[3];
  const float* pw2      = (const float*)d_in[4];
  const float* a_wih    = (const float*)d_in[5];
  const float* a_whh    = (const float*)d_in[6];
  const float* a_b      = (const float*)d_in[7];
  const float* d_wih    = (const float*)d_in[8];
  const float* d_whh    = (const float*)d_in[9];
  const float* d_b      = (const float*)d_in[10];
  const float* proj_w   = (const float*)d_in[11];
  const float* proj_b   = (const float*)d_in[12];
  const float* query_w  = (const float*)d_in[13];
  const float* memory_w = (const float*)d_in[14];
  const float* v_w      = (const float*)d_in[15];
  const float* conv_w   = (const float*)d_in[16];
  const float* ldw      = (const float*)d_in[17];

  // zero recurrent state + barrier (ws is poisoned 0xAA before every launch)
  hipMemsetAsync(d_ws, 0, WS_STATE_BYTES, stream);
  decoder_persistent_kernel<<<NB, TPB, 0, stream>>>(
      memory, dec_inp, mem_len, pw1, pw2, a_wih, a_whh, a_b,
      d_wih, d_whh, d_b, proj_w, proj_b, query_w, memory_w, v_w, conv_w, ldw,
      (float*)d_out, (float*)d_ws);
}